// Round 9
// baseline (204.972 us; speedup 1.0000x reference)
//
#include <hip/hip_runtime.h>
#include <hip/hip_bf16.h>

typedef __attribute__((ext_vector_type(8))) short short8;
typedef __attribute__((ext_vector_type(4))) float f32x4;

#define D_   1024
#define SEQ_ 2048
#define NB_  2
#define NH_  16
#define HD_  64
#define LDV_ 4096   // V^T row stride (= B*S)

using u16 = unsigned short;
using u32 = unsigned int;

static __device__ __forceinline__ u16 f2bf(float f) {
    union { __bf16 h; u16 u; } cv;
    cv.h = (__bf16)f;
    return cv.u;
}
static __device__ __forceinline__ float bf2f(u16 u) {
    union { unsigned int i; float f; } v;
    v.i = ((unsigned int)u) << 16;
    return v.f;
}
// pack two f32 -> dword of 2 bf16 (lo = a, hi = b)
static __device__ __forceinline__ u32 pkbf(float a, float b) {
    u32 r;
    asm volatile("v_cvt_pk_bf16_f32 %0, %1, %2" : "=v"(r) : "v"(a), "v"(b));
    return r;
}

// async global->LDS, 16B per lane
static __device__ __forceinline__ void glds16(const u16* g, u16* l) {
    __builtin_amdgcn_global_load_lds(
        (const __attribute__((address_space(1))) unsigned int*)g,
        (__attribute__((address_space(3))) unsigned int*)l, 16, 0, 0);
}

// ---------------- fused f32 -> bf16 convert (one launch for all 5 tensors) ----------------
__global__ __launch_bounds__(256)
void cvt_all(const float* __restrict__ x,  const float* __restrict__ wq,
             const float* __restrict__ wk, const float* __restrict__ wv,
             const float* __restrict__ wo,
             u16* __restrict__ xb,  u16* __restrict__ wqb, u16* __restrict__ wkb,
             u16* __restrict__ wvb, u16* __restrict__ wob)
{
    const int bid = blockIdx.x;
    const float* src; u16* dst; int off;
    if (bid < 2048)      { src = x;  dst = xb;  off = bid; }
    else if (bid < 2560) { src = wq; dst = wqb; off = bid - 2048; }
    else if (bid < 3072) { src = wk; dst = wkb; off = bid - 2560; }
    else if (bid < 3584) { src = wv; dst = wvb; off = bid - 3072; }
    else                 { src = wo; dst = wob; off = bid - 3584; }
    size_t i = ((size_t)off * 256 + threadIdx.x) * 8;
    float4 a = *(const float4*)&src[i];
    float4 b = *(const float4*)&src[i + 4];
    short8 o;
    o[0] = (short)f2bf(a.x); o[1] = (short)f2bf(a.y);
    o[2] = (short)f2bf(a.z); o[3] = (short)f2bf(a.w);
    o[4] = (short)f2bf(b.x); o[5] = (short)f2bf(b.y);
    o[6] = (short)f2bf(b.z); o[7] = (short)f2bf(b.w);
    *(short8*)&dst[i] = o;
}

// ---------------- bf16 GEMM core: Y[m][n] = sum_k A[m][k] * W[n][k] ----------------
// 128x128 tile, BK=32, global_load_lds staging, double-buffered linear LDS (m97 pattern).
template<int OUT_F32>
static __device__ __forceinline__
void gemm_core(const u16* __restrict__ A, const u16* __restrict__ W,
               void* __restrict__ Y, int ldY, int mBase, int nBase,
               u16* lA, u16* lB)
{
    const int t    = threadIdx.x;
    const int lane = t & 63, wid = t >> 6;
    const int wr = wid >> 1, wc = wid & 1;
    const int lr = lane & 15, lg = lane >> 4;

    f32x4 acc[4][4] = {};

    const int srow = t >> 2;         // staging row (+64 for j=1)
    const int scol = (t & 3) * 8;    // staging col (u16)
    const u16* Ag = A + (size_t)(mBase + srow) * D_ + scol;
    const u16* Wg = W + (size_t)(nBase + srow) * D_ + scol;
    const int ldsoff = t * 8;

    auto stage = [&](int buf, int kt) {
#pragma unroll
        for (int j = 0; j < 2; ++j) {
            glds16(Ag + (size_t)j * 64 * D_ + kt * 32, lA + buf * 4096 + j * 2048 + ldsoff);
            glds16(Wg + (size_t)j * 64 * D_ + kt * 32, lB + buf * 4096 + j * 2048 + ldsoff);
        }
    };

    stage(0, 0);
    asm volatile("s_waitcnt vmcnt(0)" ::: "memory");
    __syncthreads();

    int cur = 0;
    for (int kt = 0; kt < 32; ++kt) {
        if (kt < 31) stage(cur ^ 1, kt + 1);
        short8 af[4], bfv[4];
#pragma unroll
        for (int m = 0; m < 4; ++m)
            af[m] = *(const short8*)&lA[cur * 4096 + (wr * 64 + m * 16 + lr) * 32 + lg * 8];
#pragma unroll
        for (int n = 0; n < 4; ++n)
            bfv[n] = *(const short8*)&lB[cur * 4096 + (wc * 64 + n * 16 + lr) * 32 + lg * 8];
        __builtin_amdgcn_s_setprio(1);
#pragma unroll
        for (int m = 0; m < 4; ++m)
#pragma unroll
            for (int n = 0; n < 4; ++n)
                acc[m][n] = __builtin_amdgcn_mfma_f32_16x16x32_bf16(af[m], bfv[n], acc[m][n], 0, 0, 0);
        __builtin_amdgcn_s_setprio(0);
        if (kt < 31) {
            asm volatile("s_waitcnt vmcnt(0)" ::: "memory");
            __syncthreads();
        }
        cur ^= 1;
    }

#pragma unroll
    for (int m = 0; m < 4; ++m)
#pragma unroll
        for (int n = 0; n < 4; ++n)
#pragma unroll
            for (int r = 0; r < 4; ++r) {
                int row = mBase + wr * 64 + m * 16 + lg * 4 + r;
                int col = nBase + wc * 64 + n * 16 + lr;
                if (OUT_F32)
                    ((float*)Y)[(size_t)row * ldY + col] = acc[m][n][r];
                else
                    ((u16*)Y)[(size_t)row * ldY + col] = f2bf(acc[m][n][r]);
            }
}

// fused QKV: z=0 -> Q = x Wq^T, z=1 -> K = x Wk^T, z=2 -> V^T = Wv x^T
__global__ __launch_bounds__(256)
void gemm_qkv(const u16* __restrict__ xb, const u16* __restrict__ wq, const u16* __restrict__ wk,
              const u16* __restrict__ wv, u16* __restrict__ Qo, u16* __restrict__ Ko,
              u16* __restrict__ Vto)
{
    __shared__ u16 lA[2 * 128 * 32];
    __shared__ u16 lB[2 * 128 * 32];
    const int z = blockIdx.z;
    if (z == 0)
        gemm_core<0>(xb, wq, Qo, D_, blockIdx.x * 128, blockIdx.y * 128, lA, lB);
    else if (z == 1)
        gemm_core<0>(xb, wk, Ko, D_, blockIdx.x * 128, blockIdx.y * 128, lA, lB);
    else
        gemm_core<0>(wv, xb, Vto, LDV_, blockIdx.y * 128, blockIdx.x * 128, lA, lB);
}

__global__ __launch_bounds__(256)
void gemm_out(const u16* __restrict__ Ab, const u16* __restrict__ wo, float* __restrict__ out)
{
    __shared__ u16 lA[2 * 128 * 32];
    __shared__ u16 lB[2 * 128 * 32];
    gemm_core<1>(Ab, wo, out, D_, blockIdx.x * 128, blockIdx.y * 128, lA, lB);
}

// ---------------- causal flash attention (round-9: full co-residency) ----------------
// 1024 single-q-tile blocks (4 waves x 16 q-rows). LDS 27.6KB -> 5 blocks/CU capacity:
// ALL 1024 blocks resident from t=0 (4096 waves = 4/SIMD, 2x round-8 TLP).
// Heavy/light q-tiles interleaved across consecutive pid so per-CU work sums are even.
// Swapped-operand in-register softmax; K LDS dbuf (4x wave reuse, 1 barrier/iter);
// V direct from L2 (bh -> XCD-local via id&31). setprio(1) around MFMA clusters.
__global__ __launch_bounds__(256, 5)
void attn_fwd(const u16* __restrict__ Q, const u16* __restrict__ K,
              const u16* __restrict__ Vt, u16* __restrict__ O)
{
    __shared__ u16 lK[2][64][72];   // [key][hd], 144B stride -> 2-way alias (free)
    __shared__ u16 lP[4][16][72];   // per-wave P: [q][key]

    const int t    = threadIdx.x;
    const int lane = t & 63, wid = t >> 6;
    const int lr = lane & 15, lg = lane >> 4;
    const int id  = (int)blockIdx.x;
    const int bh  = id & 31;        // id%8 fixed per bh -> XCD-local K/V/Q
    const int pid = id >> 5;        // 0..31: qt sequence 31,0,30,1,... (balanced pairs)
    const int qt  = (pid & 1) ? (pid >> 1) : (31 - (pid >> 1));
    const int b = bh >> 4, h = bh & 15;

    const u16* Qb = Q  + (size_t)b * SEQ_ * D_ + h * HD_;
    const u16* Kb = K  + (size_t)b * SEQ_ * D_ + h * HD_;
    const u16* Vg = Vt + (size_t)(h * HD_) * LDV_ + (size_t)b * SEQ_;
    u16*       Ob = O  + (size_t)b * SEQ_ * D_ + h * HD_;

    const int sr = t >> 3;          // K staging row 0..31 (+32)
    const int sc = (t & 7) * 8;     // K staging col

    const int qbase = qt * 64;
    const int qrow  = qbase + wid * 16 + lr;

    // Q fragment scaled by 0.125*log2(e): softmax in exp2 domain
    short8 qf[2];
#pragma unroll
    for (int ks = 0; ks < 2; ++ks) {
        short8 v = *(const short8*)&Qb[(size_t)qrow * D_ + ks * 32 + lg * 8];
#pragma unroll
        for (int c = 0; c < 8; ++c)
            v[c] = (short)f2bf(bf2f((u16)v[c]) * 0.18033688011112042f);
        qf[ks] = v;
    }

    f32x4 accOT[4] = {};            // O^T: d = n2*16 + lg*4 + j, q = lr (within wave frag)
    float m_r = -1e30f, l_r = 0.f;

    // prologue: stage K tile 0 into buf 0
    {
        short8 k0 = *(const short8*)&Kb[(size_t)sr * D_ + sc];
        short8 k1 = *(const short8*)&Kb[(size_t)(sr + 32) * D_ + sc];
        *(short8*)&lK[0][sr][sc] = k0;  *(short8*)&lK[0][sr + 32][sc] = k1;
    }
    __syncthreads();

    int cur = 0;
    for (int kt = 0; kt <= qt; ++kt) {
        const int kb = kt * 64;

        // V fragments for THIS tile: direct from L2, issued early
        short8 vf0[4], vf1[4];
#pragma unroll
        for (int n2 = 0; n2 < 4; ++n2) {
            vf0[n2] = *(const short8*)&Vg[(size_t)(n2 * 16 + lr) * LDV_ + kb + lg * 8];
            vf1[n2] = *(const short8*)&Vg[(size_t)(n2 * 16 + lr) * LDV_ + kb + 32 + lg * 8];
        }
        // next K tile -> regs (consumed at iteration bottom)
        short8 k0, k1;
        if (kt < qt) {
            const int kn = kb + 64;
            k0 = *(const short8*)&Kb[(size_t)(kn + sr) * D_ + sc];
            k1 = *(const short8*)&Kb[(size_t)(kn + sr + 32) * D_ + sc];
        }

        // S^T = K · Q^T : st[n][j] = S[key = kb+16n+4lg+j][q = qrow]
        f32x4 st[4] = {};
        __builtin_amdgcn_s_setprio(1);
#pragma unroll
        for (int n = 0; n < 4; ++n)
#pragma unroll
            for (int ks = 0; ks < 2; ++ks) {
                short8 kf = *(const short8*)&lK[cur][n * 16 + lr][ks * 32 + lg * 8];
                st[n] = __builtin_amdgcn_mfma_f32_16x16x32_bf16(kf, qf[ks], st[n], 0, 0, 0);
            }
        __builtin_amdgcn_s_setprio(0);
        // causal mask (diagonal tile only)
        if (kt == qt) {
#pragma unroll
            for (int n = 0; n < 4; ++n)
#pragma unroll
                for (int j = 0; j < 4; ++j)
                    if (kb + n * 16 + lg * 4 + j > qrow) st[n][j] = -1e30f;
        }

        // in-register online softmax (exp2 domain); row spans 4 lg-lanes of lr
        float pmax = st[0][0];
#pragma unroll
        for (int n = 0; n < 4; ++n)
#pragma unroll
            for (int j = 0; j < 4; ++j) pmax = fmaxf(pmax, st[n][j]);
        pmax = fmaxf(pmax, __shfl_xor(pmax, 16));
        pmax = fmaxf(pmax, __shfl_xor(pmax, 32));
        const float mn = fmaxf(m_r, pmax);
        const float alpha = exp2f(m_r - mn);
        m_r = mn;
        float rsum = 0.f;
#pragma unroll
        for (int n = 0; n < 4; ++n)
#pragma unroll
            for (int j = 0; j < 4; ++j) {
                float p = exp2f(st[n][j] - mn);
                st[n][j] = p;
                rsum += p;
            }
        rsum += __shfl_xor(rsum, 16);
        rsum += __shfl_xor(rsum, 32);
        l_r = l_r * alpha + rsum;

        // P^T -> lP (rows = q), packed b64 writes; same-wave RAW, no barrier
#pragma unroll
        for (int n = 0; n < 4; ++n) {
            uint2 d;
            d.x = pkbf(st[n][0], st[n][1]);
            d.y = pkbf(st[n][2], st[n][3]);
            *(uint2*)&lP[wid][lr][n * 16 + lg * 4] = d;
        }
#pragma unroll
        for (int n2 = 0; n2 < 4; ++n2)
#pragma unroll
            for (int j = 0; j < 4; ++j) accOT[n2][j] *= alpha;

        // O^T += V^T · P^T  (V from regs, P from per-wave LDS)
        short8 pb0 = *(const short8*)&lP[wid][lr][lg * 8];
        short8 pb1 = *(const short8*)&lP[wid][lr][32 + lg * 8];
        __builtin_amdgcn_s_setprio(1);
#pragma unroll
        for (int n2 = 0; n2 < 4; ++n2) {
            accOT[n2] = __builtin_amdgcn_mfma_f32_16x16x32_bf16(vf0[n2], pb0, accOT[n2], 0, 0, 0);
            accOT[n2] = __builtin_amdgcn_mfma_f32_16x16x32_bf16(vf1[n2], pb1, accOT[n2], 0, 0, 0);
        }
        __builtin_amdgcn_s_setprio(0);

        // stage next K into other buffer
        if (kt < qt) {
            *(short8*)&lK[cur ^ 1][sr][sc] = k0;
            *(short8*)&lK[cur ^ 1][sr + 32][sc] = k1;
        }
        __syncthreads();
        cur ^= 1;
    }

    // epilogue: O[q][d] = O^T[d][q] / l (packed dword writes)
    const float inv = 1.f / l_r;
#pragma unroll
    for (int n2 = 0; n2 < 4; ++n2) {
        *(u32*)&Ob[(size_t)qrow * D_ + n2 * 16 + lg * 4]     = pkbf(accOT[n2][0] * inv, accOT[n2][1] * inv);
        *(u32*)&Ob[(size_t)qrow * D_ + n2 * 16 + lg * 4 + 2] = pkbf(accOT[n2][2] * inv, accOT[n2][3] * inv);
    }
}

extern "C" void kernel_launch(void* const* d_in, const int* in_sizes, int n_in,
                              void* d_out, int out_size, void* d_ws, size_t ws_size,
                              hipStream_t stream)
{
    const float* x  = (const float*)d_in[0];
    const float* Wq = (const float*)d_in[1];
    const float* Wk = (const float*)d_in[2];
    const float* Wv = (const float*)d_in[3];
    const float* Wo = (const float*)d_in[4];
    float* out = (float*)d_out;

    const size_t NX = (size_t)NB_ * SEQ_ * D_;  // 4194304
    const size_t NW = (size_t)D_ * D_;          // 1048576

    u16* xb  = (u16*)d_ws;
    u16* wqb = xb  + NX;
    u16* wkb = wqb + NW;
    u16* wvb = wkb + NW;
    u16* wob = wvb + NW;
    u16* Qb  = wob + NW;
    u16* Kb  = Qb  + NX;
    u16* Vtb = Kb  + NX;   // V^T: [1024][4096]
    u16* Ab  = Vtb + NX;

    cvt_all<<<dim3(4096), dim3(256), 0, stream>>>(x, Wq, Wk, Wv, Wo,
                                                  xb, wqb, wkb, wvb, wob);

    gemm_qkv<<<dim3(32, 8, 3), dim3(256), 0, stream>>>(xb, wqb, wkb, wvb, Qb, Kb, Vtb);

    // 1024 single-tile blocks, all co-resident (5 blocks/CU LDS capacity)
    attn_fwd<<<dim3(1024), dim3(256), 0, stream>>>(Qb, Kb, Vtb, Ab);

    gemm_out<<<dim3(32, 8, 1), dim3(256), 0, stream>>>(Ab, wob, out);
}

// Round 10
// 146.771 us; speedup vs baseline: 1.3965x; 1.3965x over previous
//
#include <hip/hip_runtime.h>
#include <hip/hip_bf16.h>

typedef __attribute__((ext_vector_type(8))) short short8;
typedef __attribute__((ext_vector_type(4))) float f32x4;

#define D_   1024
#define SEQ_ 2048
#define NB_  2
#define NH_  16
#define HD_  64
#define LDV_ 4096   // V^T row stride (= B*S)

using u16 = unsigned short;
using u32 = unsigned int;

static __device__ __forceinline__ u16 f2bf(float f) {
    union { __bf16 h; u16 u; } cv;
    cv.h = (__bf16)f;
    return cv.u;
}
static __device__ __forceinline__ float bf2f(u16 u) {
    union { unsigned int i; float f; } v;
    v.i = ((unsigned int)u) << 16;
    return v.f;
}
// pack two f32 -> dword of 2 bf16 (lo = a, hi = b)
static __device__ __forceinline__ u32 pkbf(float a, float b) {
    u32 r;
    asm volatile("v_cvt_pk_bf16_f32 %0, %1, %2" : "=v"(r) : "v"(a), "v"(b));
    return r;
}

// async global->LDS, 16B per lane
static __device__ __forceinline__ void glds16(const u16* g, u16* l) {
    __builtin_amdgcn_global_load_lds(
        (const __attribute__((address_space(1))) unsigned int*)g,
        (__attribute__((address_space(3))) unsigned int*)l, 16, 0, 0);
}

// qt table: 4 rows (s = (id>>3)&3) x 8 cols (t = (id>>7)&7).
// Every column sums to 62 AND every row's even-t / odd-t half sums to 62:
// per-CU 4-block windows balance under stride-8-sequential AND stride-256
// round-robin dispatch mappings (mean work = 62/4 tiles per block).
__device__ const unsigned char QT_TAB[32] = {
    31, 30,  2,  3,  4,  5, 25, 24,
     0,  1, 29, 28, 27, 26,  6,  7,
    23, 22, 10, 11, 12, 13, 17, 16,
     8,  9, 21, 20, 19, 18, 14, 15
};

// ---------------- fused f32 -> bf16 convert (one launch for all 5 tensors) ----------------
__global__ __launch_bounds__(256)
void cvt_all(const float* __restrict__ x,  const float* __restrict__ wq,
             const float* __restrict__ wk, const float* __restrict__ wv,
             const float* __restrict__ wo,
             u16* __restrict__ xb,  u16* __restrict__ wqb, u16* __restrict__ wkb,
             u16* __restrict__ wvb, u16* __restrict__ wob)
{
    const int bid = blockIdx.x;
    const float* src; u16* dst; int off;
    if (bid < 2048)      { src = x;  dst = xb;  off = bid; }
    else if (bid < 2560) { src = wq; dst = wqb; off = bid - 2048; }
    else if (bid < 3072) { src = wk; dst = wkb; off = bid - 2560; }
    else if (bid < 3584) { src = wv; dst = wvb; off = bid - 3072; }
    else                 { src = wo; dst = wob; off = bid - 3584; }
    size_t i = ((size_t)off * 256 + threadIdx.x) * 8;
    float4 a = *(const float4*)&src[i];
    float4 b = *(const float4*)&src[i + 4];
    short8 o;
    o[0] = (short)f2bf(a.x); o[1] = (short)f2bf(a.y);
    o[2] = (short)f2bf(a.z); o[3] = (short)f2bf(a.w);
    o[4] = (short)f2bf(b.x); o[5] = (short)f2bf(b.y);
    o[6] = (short)f2bf(b.z); o[7] = (short)f2bf(b.w);
    *(short8*)&dst[i] = o;
}

// ---------------- bf16 GEMM core: Y[m][n] = sum_k A[m][k] * W[n][k] ----------------
// 128x128 tile, BK=32, global_load_lds staging, double-buffered linear LDS (m97 pattern).
template<int OUT_F32>
static __device__ __forceinline__
void gemm_core(const u16* __restrict__ A, const u16* __restrict__ W,
               void* __restrict__ Y, int ldY, int mBase, int nBase,
               u16* lA, u16* lB)
{
    const int t    = threadIdx.x;
    const int lane = t & 63, wid = t >> 6;
    const int wr = wid >> 1, wc = wid & 1;
    const int lr = lane & 15, lg = lane >> 4;

    f32x4 acc[4][4] = {};

    const int srow = t >> 2;         // staging row (+64 for j=1)
    const int scol = (t & 3) * 8;    // staging col (u16)
    const u16* Ag = A + (size_t)(mBase + srow) * D_ + scol;
    const u16* Wg = W + (size_t)(nBase + srow) * D_ + scol;
    const int ldsoff = t * 8;

    auto stage = [&](int buf, int kt) {
#pragma unroll
        for (int j = 0; j < 2; ++j) {
            glds16(Ag + (size_t)j * 64 * D_ + kt * 32, lA + buf * 4096 + j * 2048 + ldsoff);
            glds16(Wg + (size_t)j * 64 * D_ + kt * 32, lB + buf * 4096 + j * 2048 + ldsoff);
        }
    };

    stage(0, 0);
    asm volatile("s_waitcnt vmcnt(0)" ::: "memory");
    __syncthreads();

    int cur = 0;
    for (int kt = 0; kt < 32; ++kt) {
        if (kt < 31) stage(cur ^ 1, kt + 1);
        short8 af[4], bfv[4];
#pragma unroll
        for (int m = 0; m < 4; ++m)
            af[m] = *(const short8*)&lA[cur * 4096 + (wr * 64 + m * 16 + lr) * 32 + lg * 8];
#pragma unroll
        for (int n = 0; n < 4; ++n)
            bfv[n] = *(const short8*)&lB[cur * 4096 + (wc * 64 + n * 16 + lr) * 32 + lg * 8];
        __builtin_amdgcn_s_setprio(1);
#pragma unroll
        for (int m = 0; m < 4; ++m)
#pragma unroll
            for (int n = 0; n < 4; ++n)
                acc[m][n] = __builtin_amdgcn_mfma_f32_16x16x32_bf16(af[m], bfv[n], acc[m][n], 0, 0, 0);
        __builtin_amdgcn_s_setprio(0);
        if (kt < 31) {
            asm volatile("s_waitcnt vmcnt(0)" ::: "memory");
            __syncthreads();
        }
        cur ^= 1;
    }

#pragma unroll
    for (int m = 0; m < 4; ++m)
#pragma unroll
        for (int n = 0; n < 4; ++n)
#pragma unroll
            for (int r = 0; r < 4; ++r) {
                int row = mBase + wr * 64 + m * 16 + lg * 4 + r;
                int col = nBase + wc * 64 + n * 16 + lr;
                if (OUT_F32)
                    ((float*)Y)[(size_t)row * ldY + col] = acc[m][n][r];
                else
                    ((u16*)Y)[(size_t)row * ldY + col] = f2bf(acc[m][n][r]);
            }
}

// fused QKV: z=0 -> Q = x Wq^T, z=1 -> K = x Wk^T, z=2 -> V^T = Wv x^T
__global__ __launch_bounds__(256)
void gemm_qkv(const u16* __restrict__ xb, const u16* __restrict__ wq, const u16* __restrict__ wk,
              const u16* __restrict__ wv, u16* __restrict__ Qo, u16* __restrict__ Ko,
              u16* __restrict__ Vto)
{
    __shared__ u16 lA[2 * 128 * 32];
    __shared__ u16 lB[2 * 128 * 32];
    const int z = blockIdx.z;
    if (z == 0)
        gemm_core<0>(xb, wq, Qo, D_, blockIdx.x * 128, blockIdx.y * 128, lA, lB);
    else if (z == 1)
        gemm_core<0>(xb, wk, Ko, D_, blockIdx.x * 128, blockIdx.y * 128, lA, lB);
    else
        gemm_core<0>(wv, xb, Vto, LDV_, blockIdx.y * 128, blockIdx.x * 128, lA, lB);
}

__global__ __launch_bounds__(256)
void gemm_out(const u16* __restrict__ Ab, const u16* __restrict__ wo, float* __restrict__ out)
{
    __shared__ u16 lA[2 * 128 * 32];
    __shared__ u16 lB[2 * 128 * 32];
    gemm_core<1>(Ab, wo, out, D_, blockIdx.x * 128, blockIdx.y * 128, lA, lB);
}

// ---------------- causal flash attention (round-10) ----------------
// 1024 single-q-tile blocks (4 waves x 16 q-rows), 27.6KB LDS -> all co-resident
// (4 blocks/CU, 16 waves/CU). NO forced launch-bounds cap (round-9's VGPR-48 spill
// regression: WRITE_SIZE 8.4->23MB scratch). Work balance via QT_TAB (balanced under
// both plausible dispatch mappings). Swapped-operand in-register softmax + defer-max;
// K LDS dbuf (4x wave reuse, 1 barrier/iter); V direct from L2 (XCD-local, id&7).
__global__ __launch_bounds__(256)
void attn_fwd(const u16* __restrict__ Q, const u16* __restrict__ K,
              const u16* __restrict__ Vt, u16* __restrict__ O)
{
    __shared__ u16 lK[2][64][72];   // [key][hd], 144B stride -> 2-way alias (free)
    __shared__ u16 lP[4][16][72];   // per-wave P: [q][key]

    const int t    = threadIdx.x;
    const int lane = t & 63, wid = t >> 6;
    const int lr = lane & 15, lg = lane >> 4;
    const int id  = (int)blockIdx.x;
    // bits: [2:0]=XCD/bh-low, [4:3]=s (balance slot), [6:5]=bh-high, [9:7]=t
    const int bh  = (id & 7) | (((id >> 5) & 3) << 3);   // bh%8 = XCD -> K/V L2-local
    const int qt  = QT_TAB[((id >> 3) & 3) * 8 + ((id >> 7) & 7)];
    const int b = bh >> 4, h = bh & 15;

    const u16* Qb = Q  + (size_t)b * SEQ_ * D_ + h * HD_;
    const u16* Kb = K  + (size_t)b * SEQ_ * D_ + h * HD_;
    const u16* Vg = Vt + (size_t)(h * HD_) * LDV_ + (size_t)b * SEQ_;
    u16*       Ob = O  + (size_t)b * SEQ_ * D_ + h * HD_;

    const int sr = t >> 3;          // K staging row 0..31 (+32)
    const int sc = (t & 7) * 8;     // K staging col

    const int qbase = qt * 64;
    const int qrow  = qbase + wid * 16 + lr;

    // Q fragment scaled by 0.125*log2(e): softmax in exp2 domain
    short8 qf[2];
#pragma unroll
    for (int ks = 0; ks < 2; ++ks) {
        short8 v = *(const short8*)&Qb[(size_t)qrow * D_ + ks * 32 + lg * 8];
#pragma unroll
        for (int c = 0; c < 8; ++c)
            v[c] = (short)f2bf(bf2f((u16)v[c]) * 0.18033688011112042f);
        qf[ks] = v;
    }

    f32x4 accOT[4] = {};            // O^T: d = n2*16 + lg*4 + j, q = lr (within wave frag)
    float m_r = -1e30f, l_r = 0.f;

    // prologue: stage K tile 0 into buf 0
    {
        short8 k0 = *(const short8*)&Kb[(size_t)sr * D_ + sc];
        short8 k1 = *(const short8*)&Kb[(size_t)(sr + 32) * D_ + sc];
        *(short8*)&lK[0][sr][sc] = k0;  *(short8*)&lK[0][sr + 32][sc] = k1;
    }
    __syncthreads();

    int cur = 0;
    for (int kt = 0; kt <= qt; ++kt) {
        const int kb = kt * 64;

        // V fragments for THIS tile: direct from L2, issued early
        short8 vf0[4], vf1[4];
#pragma unroll
        for (int n2 = 0; n2 < 4; ++n2) {
            vf0[n2] = *(const short8*)&Vg[(size_t)(n2 * 16 + lr) * LDV_ + kb + lg * 8];
            vf1[n2] = *(const short8*)&Vg[(size_t)(n2 * 16 + lr) * LDV_ + kb + 32 + lg * 8];
        }
        // next K tile -> regs (consumed at iteration bottom)
        short8 k0, k1;
        if (kt < qt) {
            const int kn = kb + 64;
            k0 = *(const short8*)&Kb[(size_t)(kn + sr) * D_ + sc];
            k1 = *(const short8*)&Kb[(size_t)(kn + sr + 32) * D_ + sc];
        }

        // S^T = K · Q^T : st[n][j] = S[key = kb+16n+4lg+j][q = qrow]
        f32x4 st[4] = {};
        __builtin_amdgcn_s_setprio(1);
#pragma unroll
        for (int n = 0; n < 4; ++n)
#pragma unroll
            for (int ks = 0; ks < 2; ++ks) {
                short8 kf = *(const short8*)&lK[cur][n * 16 + lr][ks * 32 + lg * 8];
                st[n] = __builtin_amdgcn_mfma_f32_16x16x32_bf16(kf, qf[ks], st[n], 0, 0, 0);
            }
        __builtin_amdgcn_s_setprio(0);
        // causal mask (diagonal tile only)
        if (kt == qt) {
#pragma unroll
            for (int n = 0; n < 4; ++n)
#pragma unroll
                for (int j = 0; j < 4; ++j)
                    if (kb + n * 16 + lg * 4 + j > qrow) st[n][j] = -1e30f;
        }

        // in-register online softmax (exp2 domain); row spans 4 lg-lanes of lr
        float pmax = st[0][0];
#pragma unroll
        for (int n = 0; n < 4; ++n)
#pragma unroll
            for (int j = 0; j < 4; ++j) pmax = fmaxf(pmax, st[n][j]);
        pmax = fmaxf(pmax, __shfl_xor(pmax, 16));
        pmax = fmaxf(pmax, __shfl_xor(pmax, 32));
        // defer-max (T13, THR=8): rescale only when the running max grew materially.
        // P values are then bounded by 2^8; f32 accum + final 1/l normalize absorb it.
        if (!__all(pmax <= m_r + 8.f)) {
            const float mn = fmaxf(m_r, pmax);
            const float al = exp2f(m_r - mn);
            m_r = mn;
            l_r *= al;
#pragma unroll
            for (int n2 = 0; n2 < 4; ++n2)
#pragma unroll
                for (int j = 0; j < 4; ++j) accOT[n2][j] *= al;
        }
        float rsum = 0.f;
#pragma unroll
        for (int n = 0; n < 4; ++n)
#pragma unroll
            for (int j = 0; j < 4; ++j) {
                float p = exp2f(st[n][j] - m_r);
                st[n][j] = p;
                rsum += p;
            }
        rsum += __shfl_xor(rsum, 16);
        rsum += __shfl_xor(rsum, 32);
        l_r += rsum;

        // P^T -> lP (rows = q), packed b64 writes; same-wave RAW, no barrier
#pragma unroll
        for (int n = 0; n < 4; ++n) {
            uint2 d;
            d.x = pkbf(st[n][0], st[n][1]);
            d.y = pkbf(st[n][2], st[n][3]);
            *(uint2*)&lP[wid][lr][n * 16 + lg * 4] = d;
        }

        // O^T += V^T · P^T  (V from regs, P from per-wave LDS)
        short8 pb0 = *(const short8*)&lP[wid][lr][lg * 8];
        short8 pb1 = *(const short8*)&lP[wid][lr][32 + lg * 8];
        __builtin_amdgcn_s_setprio(1);
#pragma unroll
        for (int n2 = 0; n2 < 4; ++n2) {
            accOT[n2] = __builtin_amdgcn_mfma_f32_16x16x32_bf16(vf0[n2], pb0, accOT[n2], 0, 0, 0);
            accOT[n2] = __builtin_amdgcn_mfma_f32_16x16x32_bf16(vf1[n2], pb1, accOT[n2], 0, 0, 0);
        }
        __builtin_amdgcn_s_setprio(0);

        // stage next K into other buffer
        if (kt < qt) {
            *(short8*)&lK[cur ^ 1][sr][sc] = k0;
            *(short8*)&lK[cur ^ 1][sr + 32][sc] = k1;
        }
        __syncthreads();
        cur ^= 1;
    }

    // epilogue: O[q][d] = O^T[d][q] / l (packed dword writes)
    const float inv = 1.f / l_r;
#pragma unroll
    for (int n2 = 0; n2 < 4; ++n2) {
        *(u32*)&Ob[(size_t)qrow * D_ + n2 * 16 + lg * 4]     = pkbf(accOT[n2][0] * inv, accOT[n2][1] * inv);
        *(u32*)&Ob[(size_t)qrow * D_ + n2 * 16 + lg * 4 + 2] = pkbf(accOT[n2][2] * inv, accOT[n2][3] * inv);
    }
}

extern "C" void kernel_launch(void* const* d_in, const int* in_sizes, int n_in,
                              void* d_out, int out_size, void* d_ws, size_t ws_size,
                              hipStream_t stream)
{
    const float* x  = (const float*)d_in[0];
    const float* Wq = (const float*)d_in[1];
    const float* Wk = (const float*)d_in[2];
    const float* Wv = (const float*)d_in[3];
    const float* Wo = (const float*)d_in[4];
    float* out = (float*)d_out;

    const size_t NX = (size_t)NB_ * SEQ_ * D_;  // 4194304
    const size_t NW = (size_t)D_ * D_;          // 1048576

    u16* xb  = (u16*)d_ws;
    u16* wqb = xb  + NX;
    u16* wkb = wqb + NW;
    u16* wvb = wkb + NW;
    u16* wob = wvb + NW;
    u16* Qb  = wob + NW;
    u16* Kb  = Qb  + NX;
    u16* Vtb = Kb  + NX;   // V^T: [1024][4096]
    u16* Ab  = Vtb + NX;

    cvt_all<<<dim3(4096), dim3(256), 0, stream>>>(x, Wq, Wk, Wv, Wo,
                                                  xb, wqb, wkb, wvb, wob);

    gemm_qkv<<<dim3(32, 8, 3), dim3(256), 0, stream>>>(xb, wqb, wkb, wvb, Qb, Kb, Vtb);

    // 1024 single-tile blocks, all co-resident (4/CU), QT_TAB-balanced
    attn_fwd<<<dim3(1024), dim3(256), 0, stream>>>(Qb, Kb, Vtb, Ab);

    gemm_out<<<dim3(32, 8, 1), dim3(256), 0, stream>>>(Ab, wob, out);
}

// Round 11
// 137.186 us; speedup vs baseline: 1.4941x; 1.0699x over previous
//
#include <hip/hip_runtime.h>
#include <hip/hip_bf16.h>

typedef __attribute__((ext_vector_type(8))) short short8;
typedef __attribute__((ext_vector_type(4))) float f32x4;
typedef __attribute__((ext_vector_type(16))) float f32x16;

#define D_   1024
#define SEQ_ 2048
#define NB_  2
#define NH_  16
#define HD_  64
#define LDV_ 4096   // V^T row stride (= B*S)

using u16 = unsigned short;
using u32 = unsigned int;

static __device__ __forceinline__ u16 f2bf(float f) {
    union { __bf16 h; u16 u; } cv;
    cv.h = (__bf16)f;
    return cv.u;
}
static __device__ __forceinline__ float bf2f(u16 u) {
    union { unsigned int i; float f; } v;
    v.i = ((unsigned int)u) << 16;
    return v.f;
}
// pack two f32 -> dword of 2 bf16 (lo = a, hi = b)
static __device__ __forceinline__ u32 pkbf(float a, float b) {
    u32 r;
    asm volatile("v_cvt_pk_bf16_f32 %0, %1, %2" : "=v"(r) : "v"(a), "v"(b));
    return r;
}

// async global->LDS, 16B per lane
static __device__ __forceinline__ void glds16(const u16* g, u16* l) {
    __builtin_amdgcn_global_load_lds(
        (const __attribute__((address_space(1))) unsigned int*)g,
        (__attribute__((address_space(3))) unsigned int*)l, 16, 0, 0);
}

// ---------------- fused f32 -> bf16 convert (one launch for all 5 tensors) ----------------
__global__ __launch_bounds__(256)
void cvt_all(const float* __restrict__ x,  const float* __restrict__ wq,
             const float* __restrict__ wk, const float* __restrict__ wv,
             const float* __restrict__ wo,
             u16* __restrict__ xb,  u16* __restrict__ wqb, u16* __restrict__ wkb,
             u16* __restrict__ wvb, u16* __restrict__ wob)
{
    const int bid = blockIdx.x;
    const float* src; u16* dst; int off;
    if (bid < 2048)      { src = x;  dst = xb;  off = bid; }
    else if (bid < 2560) { src = wq; dst = wqb; off = bid - 2048; }
    else if (bid < 3072) { src = wk; dst = wkb; off = bid - 2560; }
    else if (bid < 3584) { src = wv; dst = wvb; off = bid - 3072; }
    else                 { src = wo; dst = wob; off = bid - 3584; }
    size_t i = ((size_t)off * 256 + threadIdx.x) * 8;
    float4 a = *(const float4*)&src[i];
    float4 b = *(const float4*)&src[i + 4];
    short8 o;
    o[0] = (short)f2bf(a.x); o[1] = (short)f2bf(a.y);
    o[2] = (short)f2bf(a.z); o[3] = (short)f2bf(a.w);
    o[4] = (short)f2bf(b.x); o[5] = (short)f2bf(b.y);
    o[6] = (short)f2bf(b.z); o[7] = (short)f2bf(b.w);
    *(short8*)&dst[i] = o;
}

// ---------------- bf16 GEMM core: Y[m][n] = sum_k A[m][k] * W[n][k] ----------------
// 128x128 tile, BK=32, global_load_lds staging, double-buffered linear LDS (m97 pattern).
template<int OUT_F32>
static __device__ __forceinline__
void gemm_core(const u16* __restrict__ A, const u16* __restrict__ W,
               void* __restrict__ Y, int ldY, int mBase, int nBase,
               u16* lA, u16* lB)
{
    const int t    = threadIdx.x;
    const int lane = t & 63, wid = t >> 6;
    const int wr = wid >> 1, wc = wid & 1;
    const int lr = lane & 15, lg = lane >> 4;

    f32x4 acc[4][4] = {};

    const int srow = t >> 2;         // staging row (+64 for j=1)
    const int scol = (t & 3) * 8;    // staging col (u16)
    const u16* Ag = A + (size_t)(mBase + srow) * D_ + scol;
    const u16* Wg = W + (size_t)(nBase + srow) * D_ + scol;
    const int ldsoff = t * 8;

    auto stage = [&](int buf, int kt) {
#pragma unroll
        for (int j = 0; j < 2; ++j) {
            glds16(Ag + (size_t)j * 64 * D_ + kt * 32, lA + buf * 4096 + j * 2048 + ldsoff);
            glds16(Wg + (size_t)j * 64 * D_ + kt * 32, lB + buf * 4096 + j * 2048 + ldsoff);
        }
    };

    stage(0, 0);
    asm volatile("s_waitcnt vmcnt(0)" ::: "memory");
    __syncthreads();

    int cur = 0;
    for (int kt = 0; kt < 32; ++kt) {
        if (kt < 31) stage(cur ^ 1, kt + 1);
        short8 af[4], bfv[4];
#pragma unroll
        for (int m = 0; m < 4; ++m)
            af[m] = *(const short8*)&lA[cur * 4096 + (wr * 64 + m * 16 + lr) * 32 + lg * 8];
#pragma unroll
        for (int n = 0; n < 4; ++n)
            bfv[n] = *(const short8*)&lB[cur * 4096 + (wc * 64 + n * 16 + lr) * 32 + lg * 8];
        __builtin_amdgcn_s_setprio(1);
#pragma unroll
        for (int m = 0; m < 4; ++m)
#pragma unroll
            for (int n = 0; n < 4; ++n)
                acc[m][n] = __builtin_amdgcn_mfma_f32_16x16x32_bf16(af[m], bfv[n], acc[m][n], 0, 0, 0);
        __builtin_amdgcn_s_setprio(0);
        if (kt < 31) {
            asm volatile("s_waitcnt vmcnt(0)" ::: "memory");
            __syncthreads();
        }
        cur ^= 1;
    }

#pragma unroll
    for (int m = 0; m < 4; ++m)
#pragma unroll
        for (int n = 0; n < 4; ++n)
#pragma unroll
            for (int r = 0; r < 4; ++r) {
                int row = mBase + wr * 64 + m * 16 + lg * 4 + r;
                int col = nBase + wc * 64 + n * 16 + lr;
                if (OUT_F32)
                    ((float*)Y)[(size_t)row * ldY + col] = acc[m][n][r];
                else
                    ((u16*)Y)[(size_t)row * ldY + col] = f2bf(acc[m][n][r]);
            }
}

// fused QKV: z=0 -> Q = x Wq^T, z=1 -> K = x Wk^T, z=2 -> V^T = Wv x^T
__global__ __launch_bounds__(256)
void gemm_qkv(const u16* __restrict__ xb, const u16* __restrict__ wq, const u16* __restrict__ wk,
              const u16* __restrict__ wv, u16* __restrict__ Qo, u16* __restrict__ Ko,
              u16* __restrict__ Vto)
{
    __shared__ u16 lA[2 * 128 * 32];
    __shared__ u16 lB[2 * 128 * 32];
    const int z = blockIdx.z;
    if (z == 0)
        gemm_core<0>(xb, wq, Qo, D_, blockIdx.x * 128, blockIdx.y * 128, lA, lB);
    else if (z == 1)
        gemm_core<0>(xb, wk, Ko, D_, blockIdx.x * 128, blockIdx.y * 128, lA, lB);
    else
        gemm_core<0>(wv, xb, Vto, LDV_, blockIdx.y * 128, blockIdx.x * 128, lA, lB);
}

__global__ __launch_bounds__(256)
void gemm_out(const u16* __restrict__ Ab, const u16* __restrict__ wo, float* __restrict__ out)
{
    __shared__ u16 lA[2 * 128 * 32];
    __shared__ u16 lB[2 * 128 * 32];
    gemm_core<1>(Ab, wo, out, D_, blockIdx.x * 128, blockIdx.y * 128, lA, lB);
}

// ---------------- causal flash attention (round-11: 32x32 MFMA, zero-LDS, zero-barrier) ----------------
// 1 wave / 32 q-rows. All fragments in registers:
//   S^T = mfma_32x32x16(K, Q): lane holds 32 scores of ONE q-row (q = lane&31);
//   softmax: in-register tree + 1 shfl_xor(32); P -> bf16 A-frag via cvt_pk + permlane32_swap;
//   O = mfma(PA, V^T-frag) -> row-major O (col = hd = lane&31), coalesced stores.
// K prefetched one tile ahead from L2 (r4 lesson); V loaded at iter top, used ~300cy later.
// Wave processes q-groups (63-px) then px: uniform 33 iters -> balance independent of
// dispatch mapping. 1024 waves, all resident. No LDS, no barriers, no spill cap.
__global__ __launch_bounds__(64)
void attn_fwd(const u16* __restrict__ Q, const u16* __restrict__ K,
              const u16* __restrict__ Vt, u16* __restrict__ O)
{
    const int l  = threadIdx.x;
    const int lq = l & 31;          // q-col within tile / hd-col
    const int hk = l >> 5;          // k-half selector (0/1)
    const int id = (int)blockIdx.x;
    const int bh = (id & 7) | (((id >> 3) & 3) << 3);  // id%8 -> XCD-local K/V
    const int px = id >> 5;         // 0..31
    const int b = bh >> 4, h = bh & 15;

    const u16* Qb = Q  + (size_t)b * SEQ_ * D_ + h * HD_;
    const u16* Kb = K  + (size_t)b * SEQ_ * D_ + h * HD_;
    const u16* Vg = Vt + (size_t)(h * HD_) * LDV_ + (size_t)b * SEQ_;
    u16*       Ob = O  + (size_t)b * SEQ_ * D_ + h * HD_;

#pragma unroll 1
    for (int half = 0; half < 2; ++half) {
        const int g     = half ? px : (63 - px);   // 32-row q-group
        const int qbase = g * 32;
        const int qrow  = qbase + lq;
        const int ktmax = g >> 1;

        // Q fragments (B-operand): qf[c][i] = Q[qrow][16c + 8hk + i], scaled by 0.125*log2(e)
        short8 qf[4];
#pragma unroll
        for (int c = 0; c < 4; ++c) {
            short8 v = *(const short8*)&Qb[(size_t)qrow * D_ + c * 16 + hk * 8];
#pragma unroll
            for (int i = 0; i < 8; ++i)
                v[i] = (short)f2bf(bf2f((u16)v[i]) * 0.18033688011112042f);
            qf[c] = v;
        }

        f32x16 accO[2] = {};        // O[q][hd]: col=hd=32t+lq, row=q=(r&3)+8(r>>2)+4hk
        float m_r = -1e30f, l_r = 0.f;

        // K prefetch tile 0 (A-operand: row=key=32t+lq, k=hd=16c+8hk+i)
        short8 kf[2][4];
#pragma unroll
        for (int t = 0; t < 2; ++t)
#pragma unroll
            for (int c = 0; c < 4; ++c)
                kf[t][c] = *(const short8*)&Kb[(size_t)(t * 32 + lq) * D_ + c * 16 + hk * 8];

        for (int kt = 0; kt <= ktmax; ++kt) {
            const int kb = kt * 64;

            // V fragments (B-operand of PV): row=hd=32t+lq, k=key=16c+8hk+i; from V^T, L2
            short8 vf[2][4];
#pragma unroll
            for (int t = 0; t < 2; ++t)
#pragma unroll
                for (int c = 0; c < 4; ++c)
                    vf[t][c] = *(const short8*)&Vg[(size_t)(t * 32 + lq) * LDV_ + kb + c * 16 + hk * 8];

            // S^T = K · Q^T: st[t][r] = S[key = kb+32t+(r&3)+8(r>>2)+4hk][q = qrow]
            f32x16 st[2] = {};
#pragma unroll
            for (int t = 0; t < 2; ++t)
#pragma unroll
                for (int c = 0; c < 4; ++c)
                    st[t] = __builtin_amdgcn_mfma_f32_32x32x16_bf16(kf[t][c], qf[c], st[t], 0, 0, 0);

            // prefetch next K tile (lands during softmax+PV)
            if (kt < ktmax) {
#pragma unroll
                for (int t = 0; t < 2; ++t)
#pragma unroll
                    for (int c = 0; c < 4; ++c)
                        kf[t][c] = *(const short8*)&Kb[(size_t)(kb + 64 + t * 32 + lq) * D_ + c * 16 + hk * 8];
            }

            // causal mask (diagonal tile only)
            if (kt == ktmax) {
#pragma unroll
                for (int t = 0; t < 2; ++t)
#pragma unroll
                    for (int r = 0; r < 16; ++r)
                        if (kb + t * 32 + (r & 3) + 8 * (r >> 2) + 4 * hk > qrow)
                            st[t][r] = -1e30f;
            }

            // in-register online softmax (exp2 domain); partner lane^32 holds the other 32 keys
            float m0 = fmaxf(st[0][0], st[0][1]), m1 = fmaxf(st[0][2], st[0][3]);
            float m2 = fmaxf(st[0][4], st[0][5]), m3 = fmaxf(st[0][6], st[0][7]);
#pragma unroll
            for (int r = 8; r < 16; r += 4) {
                m0 = fmaxf(m0, fmaxf(st[0][r], st[0][r + 1]));
                m1 = fmaxf(m1, fmaxf(st[0][r + 2], st[0][r + 3]));
            }
#pragma unroll
            for (int r = 0; r < 16; r += 4) {
                m2 = fmaxf(m2, fmaxf(st[1][r], st[1][r + 1]));
                m3 = fmaxf(m3, fmaxf(st[1][r + 2], st[1][r + 3]));
            }
            float pmax = fmaxf(fmaxf(m0, m1), fmaxf(m2, m3));
            pmax = fmaxf(pmax, __shfl_xor(pmax, 32));
            // defer-max (T13, THR=8)
            if (!__all(pmax <= m_r + 8.f)) {
                const float mn = fmaxf(m_r, pmax);
                const float al = exp2f(m_r - mn);
                m_r = mn;
                l_r *= al;
#pragma unroll
                for (int t = 0; t < 2; ++t)
#pragma unroll
                    for (int r = 0; r < 16; ++r) accO[t][r] *= al;
            }
            float rs0 = 0.f, rs1 = 0.f;
#pragma unroll
            for (int t = 0; t < 2; ++t)
#pragma unroll
                for (int r = 0; r < 16; r += 2) {
                    float p0 = exp2f(st[t][r]     - m_r);
                    float p1 = exp2f(st[t][r + 1] - m_r);
                    st[t][r] = p0; st[t][r + 1] = p1;
                    rs0 += p0; rs1 += p1;
                }
            float rsum = rs0 + rs1;
            rsum += __shfl_xor(rsum, 32);
            l_r += rsum;

            // PA build (T12): per 16-key chunk c, 4 cvt_pk + 2 permlane32_swap -> A-frag
            // frag words = [s0.x, s1.x, s0.y, s1.y]; verified key layout:
            // lo-half lanes get keys {0,1},{2,3},{4,5},{6,7}; hi-half {8..15} (chunk-local)
            short8 pa[4];
#pragma unroll
            for (int c = 0; c < 4; ++c) {
                const int tt = c >> 1, base = (c & 1) * 8;
                u32 a0 = pkbf(st[tt][base + 0], st[tt][base + 1]);
                u32 b0 = pkbf(st[tt][base + 4], st[tt][base + 5]);
                u32 a1 = pkbf(st[tt][base + 2], st[tt][base + 3]);
                u32 b1 = pkbf(st[tt][base + 6], st[tt][base + 7]);
                asm volatile("v_permlane32_swap_b32 %0, %1" : "+v"(a0), "+v"(b0));
                asm volatile("v_permlane32_swap_b32 %0, %1" : "+v"(a1), "+v"(b1));
                union { u32 w[4]; short8 s; } u;
                u.w[0] = a0; u.w[1] = a1; u.w[2] = b0; u.w[3] = b1;
                pa[c] = u.s;
            }

            // O += P · V : accO[t] over hd-tile t
#pragma unroll
            for (int t = 0; t < 2; ++t)
#pragma unroll
                for (int c = 0; c < 4; ++c)
                    accO[t] = __builtin_amdgcn_mfma_f32_32x32x16_bf16(pa[c], vf[t][c], accO[t], 0, 0, 0);
        }

        // epilogue: O[q][hd] = accO / l; l_r lives at lane (q&31) -> gather via shfl
        const float inv = 1.f / l_r;
#pragma unroll
        for (int r = 0; r < 16; ++r) {
            const int qe = (r & 3) + 8 * (r >> 2) + 4 * hk;   // 0..31
            const float li = __shfl(inv, qe);
            const size_t qoff = (size_t)(qbase + qe) * D_;
#pragma unroll
            for (int t = 0; t < 2; ++t)
                Ob[qoff + t * 32 + lq] = f2bf(accO[t][r] * li);
        }
    }
}

extern "C" void kernel_launch(void* const* d_in, const int* in_sizes, int n_in,
                              void* d_out, int out_size, void* d_ws, size_t ws_size,
                              hipStream_t stream)
{
    const float* x  = (const float*)d_in[0];
    const float* Wq = (const float*)d_in[1];
    const float* Wk = (const float*)d_in[2];
    const float* Wv = (const float*)d_in[3];
    const float* Wo = (const float*)d_in[4];
    float* out = (float*)d_out;

    const size_t NX = (size_t)NB_ * SEQ_ * D_;  // 4194304
    const size_t NW = (size_t)D_ * D_;          // 1048576

    u16* xb  = (u16*)d_ws;
    u16* wqb = xb  + NX;
    u16* wkb = wqb + NW;
    u16* wvb = wkb + NW;
    u16* wob = wvb + NW;
    u16* Qb  = wob + NW;
    u16* Kb  = Qb  + NX;
    u16* Vtb = Kb  + NX;   // V^T: [1024][4096]
    u16* Ab  = Vtb + NX;

    cvt_all<<<dim3(4096), dim3(256), 0, stream>>>(x, Wq, Wk, Wv, Wo,
                                                  xb, wqb, wkb, wvb, wob);

    gemm_qkv<<<dim3(32, 8, 3), dim3(256), 0, stream>>>(xb, wqb, wkb, wvb, Qb, Kb, Vtb);

    // 1024 one-wave blocks, uniform 33 iters each (paired q-groups), all resident
    attn_fwd<<<dim3(1024), dim3(64), 0, stream>>>(Qb, Kb, Vtb, Ab);

    gemm_out<<<dim3(32, 8, 1), dim3(256), 0, stream>>>(Ab, wob, out);
}